// Round 17
// baseline (102.173 us; speedup 1.0000x reference)
//
#include <hip/hip_runtime.h>
#include <hip/hip_bf16.h>
#include <stdint.h>

// SSMBlock: x -> silu(x Wg^T) -> s = xg Wsp^T -> scan(decay) -> out = states WcT^T + xg W2^T + b_out
// R16 = R15 + depth-2 tile prefetch: 3 LDS buffers (96 KB, 1 block/CU), stage(t+2)
// per iter, top wait vmcnt(8) -> prefetch lead = 2 full iterations (~HBM latency).
// F32A: ar[2] register ping-pong (static idx), vmcnt(6) top wait.

typedef __bf16 bf16_t;
typedef bf16_t bf16x8 __attribute__((ext_vector_type(8)));
typedef bf16_t bf16x4 __attribute__((ext_vector_type(4)));
typedef float  f32x4  __attribute__((ext_vector_type(4)));

static __device__ __forceinline__ void async_copy16(bf16_t* lds, const bf16_t* g) {
    __builtin_amdgcn_global_load_lds((const __attribute__((address_space(1))) void*)g,
                                     (__attribute__((address_space(3))) void*)lds, 16, 0, 0);
}

// Shared GEMM body: 512 thr / 8 waves (2x4); tile 128x128, BK=64; wave tile 64x32;
// acc 4x2. LDS [row(128)][k(64)] bf16 per buffer, phys chunk16 = k_chunk ^ (row&7);
// 1KB-window gll staging (verified R9). 3 buffers, buf = t%3 (static in unrolled loop).
// K-loop: stage(t+2); vmcnt(8) [tiles t+1,t+2 in flight, t done]; s_barrier;
// ds_read+MFMA; s_barrier. Tails static: vmcnt(4) then vmcnt(0).
// Buffer WAR: buf[(t+2)%3] last read at iter t-1, end-barrier crossed before iter t.
// MODE: 0 = f32 out (+bias), 1 = bf16 out (+bias), 2 = silu -> bf16 (+bias)
// SCAN: fold 32-row sub-chunk carries from eps tile (G2 only; MODE must be 1).
template <int MODE, int NT, bool SCAN, bool F32A>
static __device__ __forceinline__ void gemm_body(
    int bid, int nwg, bf16_t* __restrict__ AsB, bf16_t* __restrict__ BsB,
    const void* __restrict__ A0v, const bf16_t* __restrict__ W0,
    const bf16_t* __restrict__ A1, const bf16_t* __restrict__ W1,
    const float* __restrict__ bias, void* __restrict__ outp,
    const float* __restrict__ decay_g, float* __restrict__ carry_g)
{
    constexpr int K = 512;
    const int tid = threadIdx.x;
    if ((nwg & 7) == 0) bid = (bid & 7) * (nwg >> 3) + (bid >> 3);   // XCD swizzle
    const int m0 = (bid >> 2) << 7, n0 = (bid & 3) << 7;   // tN = 512/128 = 4
    const int l = tid & 63, w = tid >> 6;                  // 8 waves
    const int wr = w >> 2, wc = w & 3;                     // 2 x 4 wave grid
    const int lr = l & 15, kc = l >> 4;
    const int rloc = l >> 3, sc = (l & 7) ^ rloc;          // gll source permutation

    float bv[2];
    #pragma unroll
    for (int j = 0; j < 2; ++j)
        bv[j] = bias ? bias[n0 + wc * 32 + j * 16 + lr] : 0.f;

    f32x4 acc[4][2];
    const f32x4 z = {0.f, 0.f, 0.f, 0.f};
    #pragma unroll
    for (int i = 0; i < 4; ++i)
        #pragma unroll
        for (int j = 0; j < 2; ++j) acc[i][j] = z;

    const bf16_t* __restrict__ A0b = (const bf16_t*)A0v;
    const float*  __restrict__ A0f = (const float*)A0v;
    const int arow = tid >> 2, aq = tid & 3;               // F32A mapping

    auto stage = [&](int t) {                              // bf16 A+B, 4 gll/wave
        const bf16_t* __restrict__ Asrc = (t < 8) ? A0b : A1;
        const bf16_t* __restrict__ Wsrc = (t < 8) ? W0 : W1;
        const int kk = (t & 7) << 6;
        bf16_t* bufA = AsB + (t % 3) * 8192;
        bf16_t* bufB = BsB + (t % 3) * 8192;
        #pragma unroll
        for (int v = 0; v < 2; ++v) {
            const int win = w * 2 + v;                     // 1KB window
            async_copy16(bufA + win * 512,
                         Asrc + (size_t)(m0 + win * 8 + rloc) * K + kk + sc * 8);
            async_copy16(bufB + win * 512,
                         Wsrc + (size_t)(n0 + win * 8 + rloc) * K + kk + sc * 8);
        }
    };
    auto stageB = [&](int t) {                             // F32A: B only, 2 gll/wave
        const int kk = (t & 7) << 6;
        bf16_t* bufB = BsB + (t % 3) * 8192;
        #pragma unroll
        for (int v = 0; v < 2; ++v) {
            const int win = w * 2 + v;
            async_copy16(bufB + win * 512,
                         W0 + (size_t)(n0 + win * 8 + rloc) * K + kk + sc * 8);
        }
    };
    float4 arA[2][4];                                      // 2-tile register ping-pong
    auto issueA = [&](int t) {                             // 4 independent float4 (64B)
        const float* p = A0f + (size_t)(m0 + arow) * K + ((t & 7) << 6) + aq * 16;
        arA[t & 1][0] = ((const float4*)p)[0];
        arA[t & 1][1] = ((const float4*)p)[1];
        arA[t & 1][2] = ((const float4*)p)[2];
        arA[t & 1][3] = ((const float4*)p)[3];
    };
    auto writeA = [&](int t) {                             // RNE cast + 2 swz ds_write
        const float4* ar = arA[t & 1];
        bf16x8 v0, v1;
        v0[0]=(bf16_t)ar[0].x; v0[1]=(bf16_t)ar[0].y; v0[2]=(bf16_t)ar[0].z; v0[3]=(bf16_t)ar[0].w;
        v0[4]=(bf16_t)ar[1].x; v0[5]=(bf16_t)ar[1].y; v0[6]=(bf16_t)ar[1].z; v0[7]=(bf16_t)ar[1].w;
        v1[0]=(bf16_t)ar[2].x; v1[1]=(bf16_t)ar[2].y; v1[2]=(bf16_t)ar[2].z; v1[3]=(bf16_t)ar[2].w;
        v1[4]=(bf16_t)ar[3].x; v1[5]=(bf16_t)ar[3].y; v1[6]=(bf16_t)ar[3].z; v1[7]=(bf16_t)ar[3].w;
        bf16_t* bufA = AsB + (t % 3) * 8192;
        *(bf16x8*)(bufA + arow * 64 + (((aq * 2    ) ^ (arow & 7)) << 3)) = v0;
        *(bf16x8*)(bufA + arow * 64 + (((aq * 2 + 1) ^ (arow & 7)) << 3)) = v1;
    };

    if (F32A) { issueA(0); asm volatile("" ::: "memory"); stageB(0);
                issueA(1); asm volatile("" ::: "memory"); stageB(1); }
    else      { stage(0); stage(1); }

    #pragma unroll
    for (int t = 0; t < NT; ++t) {
        if (F32A) {
            // top wait: tile t's A-regs + B-LDS done; tile t+1's 6 ops may fly
            if (t + 1 < NT) asm volatile("s_waitcnt vmcnt(6)" ::: "memory");
            else            asm volatile("s_waitcnt vmcnt(0)" ::: "memory");
            writeA(t);
            if (t + 2 < NT) {
                issueA(t + 2);                             // into ar[t&1] (just freed)
                asm volatile("" ::: "memory");             // pin A-issue before B-issue
                stageB(t + 2);
            }
            asm volatile("s_waitcnt lgkmcnt(0)" ::: "memory");   // ds_writes visible
        } else {
            if (t + 2 < NT) stage(t + 2);                  // 2-deep: +4 gll
            if (t + 2 < NT)      asm volatile("s_waitcnt vmcnt(8)" ::: "memory");
            else if (t + 1 < NT) asm volatile("s_waitcnt vmcnt(4)" ::: "memory");
            else                 asm volatile("s_waitcnt vmcnt(0)" ::: "memory");
        }
        __builtin_amdgcn_s_barrier();       // tile t visible to all waves
        const bf16_t* __restrict__ bufA = AsB + (t % 3) * 8192;
        const bf16_t* __restrict__ bufB = BsB + (t % 3) * 8192;
        bf16x8 a[2][4], b[2][2];
        #pragma unroll
        for (int ks = 0; ks < 2; ++ks) {
            #pragma unroll
            for (int i = 0; i < 4; ++i)
                a[ks][i] = *(const bf16x8*)(bufA + (wr * 64 + i * 16 + lr) * 64
                                            + (((ks * 4 + kc) ^ (lr & 7)) << 3));
            #pragma unroll
            for (int j = 0; j < 2; ++j)
                b[ks][j] = *(const bf16x8*)(bufB + (wc * 32 + j * 16 + lr) * 64
                                            + (((ks * 4 + kc) ^ (lr & 7)) << 3));
        }
        #pragma unroll
        for (int ks = 0; ks < 2; ++ks)
            #pragma unroll
            for (int i = 0; i < 4; ++i)
                #pragma unroll
                for (int j = 0; j < 2; ++j)
                    acc[i][j] = __builtin_amdgcn_mfma_f32_16x16x32_bf16(
                        a[ks][i], b[ks][j], acc[i][j], 0, 0, 0);
        if (t + 1 < NT)
            __builtin_amdgcn_s_barrier();   // reads of buf[t%3] done before overwrite
    }

    // C/D layout: col = lane&15, row = (lane>>4)*4 + reg
    if (MODE == 0) {
        float* outF = (float*)outp;
        #pragma unroll
        for (int i = 0; i < 4; ++i) {
            const int row = m0 + wr * 64 + i * 16 + kc * 4;
            #pragma unroll
            for (int j = 0; j < 2; ++j) {
                const int col = n0 + wc * 32 + j * 16 + lr;
                #pragma unroll
                for (int r = 0; r < 4; ++r)
                    outF[(size_t)(row + r) * 512 + col] = acc[i][j][r] + bv[j];
            }
        }
    } else {
        __syncthreads();                    // all waves done with K-loop LDS
        bf16_t* eps = AsB;                  // 128 x 128 bf16 = 32 KB (of 48)
        #pragma unroll
        for (int i = 0; i < 4; ++i) {
            const int row = wr * 64 + i * 16 + kc * 4;
            #pragma unroll
            for (int j = 0; j < 2; ++j) {
                const int col = wc * 32 + j * 16 + lr;
                #pragma unroll
                for (int r = 0; r < 4; ++r) {
                    float v = acc[i][j][r] + bv[j];
                    if (MODE == 2) v = v / (1.f + __expf(-v));
                    eps[(row + r) * 128 + col] = (bf16_t)v;
                }
            }
        }
        __syncthreads();
        bf16_t* outB = (bf16_t*)outp;
        #pragma unroll
        for (int s2 = 0; s2 < 4; ++s2) {    // 512 thr x 8 elems = 32 rows/pass
            const int row = s2 * 32 + (tid >> 4);
            const int col = (tid & 15) * 8;
            *(bf16x8*)(outB + (size_t)(m0 + row) * 512 + n0 + col) =
                *(const bf16x8*)(eps + row * 128 + col);
        }
        if (SCAN) {
            // fused sub-chunk carries: 4 x 32-row sub-chunks x 128 cols; all 512 thr.
            const int sub = tid >> 7, col = tid & 127;
            const int n = n0 + col;
            const float dec = decay_g[n];
            float st = 0.f;
            #pragma unroll 8
            for (int i = 0; i < 32; ++i)
                st = st * dec + (float)eps[(sub * 32 + i) * 128 + col];
            carry_g[(size_t)((m0 >> 5) + sub) * 512 + n] = st;   // 32-row chunk idx
        }
    }
}

// standalone wrapper (G2, G3): 96 KB LDS -> 1 block/CU
template <int MODE, int NT, bool SCAN, bool F32A>
__global__ __launch_bounds__(512, 2) void gemm_std(
    const void* __restrict__ A0v, const bf16_t* __restrict__ W0,
    const bf16_t* __restrict__ A1, const bf16_t* __restrict__ W1,
    const float* __restrict__ bias, void* __restrict__ outp,
    const float* __restrict__ decay_g, float* __restrict__ carry_g)
{
    __shared__ bf16_t As[3 * 128 * 64];
    __shared__ bf16_t Bs[3 * 128 * 64];
    gemm_body<MODE, NT, SCAN, F32A>(blockIdx.x, gridDim.x, As, Bs,
                                    A0v, W0, A1, W1, bias, outp, decay_g, carry_g);
}

// merged G1 (528 blocks: 0..511 = xg GEMM with f32 A; 512..527 = WcT GEMM)
__global__ __launch_bounds__(512, 2) void g1_wct(
    const float* __restrict__ x, const bf16_t* __restrict__ Wg,
    const float* __restrict__ b_gate, bf16_t* __restrict__ xg,
    const bf16_t* __restrict__ Wo, const bf16_t* __restrict__ Wsp,
    bf16_t* __restrict__ WcT)
{
    __shared__ bf16_t As[3 * 128 * 64];
    __shared__ bf16_t Bs[3 * 128 * 64];
    if (blockIdx.x < 512)
        gemm_body<2, 8, false, true>(blockIdx.x, 512, As, Bs,
            (const void*)x, Wg, (const bf16_t*)nullptr, (const bf16_t*)nullptr,
            b_gate, (void*)xg, (const float*)nullptr, (float*)nullptr);
    else
        gemm_body<1, 8, false, false>(blockIdx.x - 512, 16, As, Bs,
            (const void*)Wo, Wsp, (const bf16_t*)nullptr, (const bf16_t*)nullptr,
            (const float*)nullptr, (void*)WcT, (const float*)nullptr, (float*)nullptr);
}

// prep: weight conversion (1024 blocks) + decay (first 128 blocks). x stays f32.
__global__ void prep_all(const float* __restrict__ Wg, const float* __restrict__ Wsp,
                         const float* __restrict__ Wo, const float* __restrict__ Dp,
                         bf16_t* __restrict__ Wg_bf, bf16_t* __restrict__ Wsp_bf,
                         bf16_t* __restrict__ Wo_bf, bf16_t* __restrict__ W2_bf,
                         const float* __restrict__ A_log, float* __restrict__ decay)
{
    const int blk = blockIdx.x, tid = threadIdx.x;
    {
        int i = blk * 256 + tid;          // 512*512 elements
        Wg_bf[i]  = (bf16_t)Wg[i];
        Wsp_bf[i] = (bf16_t)Wsp[i];
        float wo  = Wo[i];
        Wo_bf[i]  = (bf16_t)wo;
        W2_bf[i]  = (bf16_t)(wo * Dp[i & 511]);   // W2[d',d] = W_out[d',d]*D[d]
    }
    if (blk < 128) {
        int d = blk * 4 + (tid >> 6);     // one wave per row of A_log
        int ll = tid & 63;
        const float* row = A_log + (size_t)d * 512;
        float s = 0.f;
        for (int k = ll; k < 512; k += 64) s += expf(row[k]);
        #pragma unroll
        for (int off = 32; off > 0; off >>= 1) s += __shfl_down(s, off);
        if (ll == 0) decay[d] = expf(-s * (1.f / 512.f));  // exp(mean(-exp(A_log)))
    }
}

// cross-chunk prefix over 128 x 32-row chunks; exc aliases carry (load-before-store,
// each thread owns column n -- no cross-thread overlap). 2048 threads.
__global__ void scan_carry(float* __restrict__ carry, const float* __restrict__ decay,
                           const float* __restrict__ state0, float* __restrict__ state_f)
{
    int g = blockIdx.x * 256 + threadIdx.x;       // B*N = 2048
    int n = g & 511, b = g >> 9;
    float dec = decay[n];
    float d32 = dec;
    #pragma unroll
    for (int t = 0; t < 5; ++t) d32 *= d32;       // dec^32 via squaring
    float st = state0[g];
    for (int ch = 0; ch < 128; ++ch) {
        size_t idx = (size_t)(b * 128 + ch) * 512 + n;
        float c = carry[idx];                      // read BEFORE overwrite
        carry[idx] = st;                           // exclusive carry-in (exc)
        st = st * d32 + c;
    }
    state_f[g] = st;                               // final state -> d_out tail
}

// 8-wide scan: thread per (b, ch32, 8n). bf16x8 loads/stores, 32 iters,
// 8 independent FMA chains. 256 blocks x 128 thr = 32768 threads.
__global__ void scan_final8(const bf16_t* __restrict__ s, const float* __restrict__ decay,
                            const float* __restrict__ exc, bf16_t* __restrict__ states)
{
    int g = blockIdx.x * 128 + threadIdx.x;       // 4 * 128 * 64 = 32768
    int ng = g & 63, ch = (g >> 6) & 127, b = g >> 13;
    const int n0 = ng * 8;
    float4 d0 = *(const float4*)(decay + n0);
    float4 d1 = *(const float4*)(decay + n0 + 4);
    const float* ep = exc + (size_t)(b * 128 + ch) * 512 + n0;
    float4 s0 = *(const float4*)ep;
    float4 s1 = *(const float4*)(ep + 4);
    float st[8] = {s0.x, s0.y, s0.z, s0.w, s1.x, s1.y, s1.z, s1.w};
    const float dc[8] = {d0.x, d0.y, d0.z, d0.w, d1.x, d1.y, d1.z, d1.w};
    size_t base = (size_t)(b * 4096 + ch * 32) * 512 + n0;
    #pragma unroll 8
    for (int i = 0; i < 32; ++i) {
        bf16x8 v = *(const bf16x8*)(s + base + (size_t)i * 512);
        bf16x8 o;
        #pragma unroll
        for (int k = 0; k < 8; ++k) {
            st[k] = st[k] * dc[k] + (float)v[k];
            o[k] = (bf16_t)st[k];
        }
        *(bf16x8*)(states + base + (size_t)i * 512) = o;
    }
}

extern "C" void kernel_launch(void* const* d_in, const int* in_sizes, int n_in,
                              void* d_out, int out_size, void* d_ws, size_t ws_size,
                              hipStream_t stream)
{
    const float* x      = (const float*)d_in[0];
    const float* state0 = (const float*)d_in[1];
    const float* W_gate = (const float*)d_in[2];
    const float* b_gate = (const float*)d_in[3];
    const float* W_sp   = (const float*)d_in[4];
    const float* b_sp   = (const float*)d_in[5];
    const float* W_out  = (const float*)d_in[6];
    const float* b_out  = (const float*)d_in[7];
    const float* A_log  = (const float*)d_in[8];
    const float* D_par  = (const float*)d_in[9];
    float* out = (float*)d_out;

    // workspace layout (~51.5 MB)
    char* ws = (char*)d_ws;
    bf16_t* states = (bf16_t*)ws;                     // 16 MB
    bf16_t* xg_bf  = (bf16_t*)(ws + (16u << 20));     // 16 MB
    bf16_t* s_bf   = (bf16_t*)(ws + (32u << 20));     // 16 MB
    bf16_t* Wg_bf  = (bf16_t*)(ws + (48u << 20));     // 5 x 512 KB weights
    bf16_t* Wsp_bf = Wg_bf + 262144;
    bf16_t* Wo_bf  = Wg_bf + 2 * 262144;
    bf16_t* W2_bf  = Wg_bf + 3 * 262144;
    bf16_t* WcT_bf = Wg_bf + 4 * 262144;
    float*  carry  = (float*)(Wg_bf + 5 * 262144);    // 1 MB (128 chunks x 512 n x B)
    float*  decay  = carry + 262144;                  // 2 KB

    prep_all<<<dim3(1024), dim3(256), 0, stream>>>(
        W_gate, W_sp, W_out, D_par, Wg_bf, Wsp_bf, Wo_bf, W2_bf, A_log, decay);

    // xg = silu(x W_gate^T + b_gate) [f32-A path] + WcT = Wo x Wsp^T (16 extra blocks)
    g1_wct<<<dim3(528), dim3(512), 0, stream>>>(
        x, Wg_bf, b_gate, xg_bf, Wo_bf, Wsp_bf, WcT_bf);

    // s = xg W_sp^T + b_sp, with fused 32-row sub-chunk carries
    gemm_std<1, 8, true, false><<<dim3(512), dim3(512), 0, stream>>>(
        (const void*)xg_bf, Wsp_bf, (const bf16_t*)nullptr, (const bf16_t*)nullptr,
        b_sp, (void*)s_bf, decay, carry);

    scan_carry<<<dim3(8), dim3(256), 0, stream>>>(carry, decay, state0, out + 8388608);
    scan_final8<<<dim3(256), dim3(128), 0, stream>>>(s_bf, decay, carry, states);

    // out = states WcT^T + xg W2^T + b_out   (concat-K, NT=16)
    gemm_std<0, 16, false, false><<<dim3(512), dim3(512), 0, stream>>>(
        (const void*)states, WcT_bf, xg_bf, W2_bf, b_out, (void*)out,
        (const float*)nullptr, (float*)nullptr);
}

// Round 18
// 83.219 us; speedup vs baseline: 1.2278x; 1.2278x over previous
//
#include <hip/hip_runtime.h>
#include <hip/hip_bf16.h>
#include <stdint.h>

// SSMBlock: x -> silu(x Wg^T) -> s = xg Wsp^T -> scan(decay) -> out = states WcT^T + xg W2^T + b_out
// R17 = exact revert to R14 (best measured: 83.08 us). 2-phase 128x128/BK=64 GEMM,
// T4 counted vmcnt, XOR-coalesced staging, 8-wave blocks, G2-fused carries,
// F32A path for G1 (no x-conversion pass). R16's depth-2/3-buffer variant regressed
// (1 block/CU + ds_write conflicts) and is abandoned.

typedef __bf16 bf16_t;
typedef bf16_t bf16x8 __attribute__((ext_vector_type(8)));
typedef bf16_t bf16x4 __attribute__((ext_vector_type(4)));
typedef float  f32x4  __attribute__((ext_vector_type(4)));

static __device__ __forceinline__ void async_copy16(bf16_t* lds, const bf16_t* g) {
    __builtin_amdgcn_global_load_lds((const __attribute__((address_space(1))) void*)g,
                                     (__attribute__((address_space(3))) void*)lds, 16, 0, 0);
}

// Block 512 thr / 8 waves (2x4); tile 128x128, BK=64; wave tile 64x32; acc 4x2 f32x4.
// LDS per buf: [row(128)][k(64)] bf16, 16 KB; phys chunk16 = k_chunk ^ (row&7).
// bf16 path (F32A=0): 16 x 1KB windows/matrix, wave owns 2 each -> 4 gll/stage;
//   K-loop: stage(t+1); vmcnt(4); s_barrier; ds_read+MFMA; s_barrier. Last iter vmcnt(0).
// f32-A path (F32A=1, G1): per thread row=tid>>2, q=tid&3; 4 float4 loads (64B),
//   RNE cast, 2 swizzled ds_write_b128. B: 2 gll/wave. Waits: top vmcnt(2) [A(t)];
//   after issue: vmcnt(6)+lgkmcnt(0) [B(t) done, writes visible]; barrier; MFMA; barrier.
// MODE: 0 = f32 out (+bias), 1 = bf16 out (+bias), 2 = silu -> bf16 (+bias)
// SCAN: fold 64-row chunk carries from eps tile (G2 only; MODE must be 1).
template <int MODE, int NT, bool SCAN, bool F32A>
__global__ __launch_bounds__(512, 4) void gemm_2ph(
    const void* __restrict__ A0v, const bf16_t* __restrict__ W0,
    const bf16_t* __restrict__ A1, const bf16_t* __restrict__ W1,
    const float* __restrict__ bias, void* __restrict__ outp,
    const float* __restrict__ decay_g, float* __restrict__ carry_g)
{
    constexpr int K = 512;
    __shared__ bf16_t As[2][128 * 64];   // 2 x 16 KB
    __shared__ bf16_t Bs[2][128 * 64];   // 2 x 16 KB
    const int tid = threadIdx.x;
    int bid = blockIdx.x;
    {   // XCD-chunked swizzle (grids are %8==0)
        int nwg = gridDim.x;
        if ((nwg & 7) == 0) bid = (bid & 7) * (nwg >> 3) + (bid >> 3);
    }
    const int m0 = (bid >> 2) << 7, n0 = (bid & 3) << 7;   // tN = 512/128 = 4
    const int l = tid & 63, w = tid >> 6;                  // 8 waves
    const int wr = w >> 2, wc = w & 3;                     // 2 x 4 wave grid
    const int lr = l & 15, kc = l >> 4;
    const int rloc = l >> 3, sc = (l & 7) ^ rloc;          // gll source permutation

    float bv[2];
    #pragma unroll
    for (int j = 0; j < 2; ++j)
        bv[j] = bias ? bias[n0 + wc * 32 + j * 16 + lr] : 0.f;

    f32x4 acc[4][2];
    const f32x4 z = {0.f, 0.f, 0.f, 0.f};
    #pragma unroll
    for (int i = 0; i < 4; ++i)
        #pragma unroll
        for (int j = 0; j < 2; ++j) acc[i][j] = z;

    const bf16_t* __restrict__ A0b = (const bf16_t*)A0v;   // bf16 path
    const float*  __restrict__ A0f = (const float*)A0v;    // f32 path
    const int arow = tid >> 2, aq = tid & 3;               // F32A mapping

    // bf16 full stage (A+B, 4 gll/wave)
    auto stage = [&](int t) {
        const bf16_t* __restrict__ Asrc = (t < 8) ? A0b : A1;
        const bf16_t* __restrict__ Wsrc = (t < 8) ? W0 : W1;
        const int kk = (t & 7) << 6;
        bf16_t* bufA = As[t & 1];
        bf16_t* bufB = Bs[t & 1];
        #pragma unroll
        for (int v = 0; v < 2; ++v) {
            const int win = w * 2 + v;          // rows win*8 .. +7 (1KB window)
            async_copy16(bufA + win * 512,
                         Asrc + (size_t)(m0 + win * 8 + rloc) * K + kk + sc * 8);
            async_copy16(bufB + win * 512,
                         Wsrc + (size_t)(n0 + win * 8 + rloc) * K + kk + sc * 8);
        }
    };
    // F32A: B-only gll stage (2/wave)
    auto stageB = [&](int t) {
        const int kk = (t & 7) << 6;
        bf16_t* bufB = Bs[t & 1];
        #pragma unroll
        for (int v = 0; v < 2; ++v) {
            const int win = w * 2 + v;
            async_copy16(bufB + win * 512,
                         W0 + (size_t)(n0 + win * 8 + rloc) * K + kk + sc * 8);
        }
    };
    float4 arA[4];
    auto issueA = [&](int t) {              // 4 independent float4 loads (64B)
        const float* p = A0f + (size_t)(m0 + arow) * K + ((t & 7) << 6) + aq * 16;
        arA[0] = ((const float4*)p)[0];
        arA[1] = ((const float4*)p)[1];
        arA[2] = ((const float4*)p)[2];
        arA[3] = ((const float4*)p)[3];
    };
    auto writeA = [&](int t) {              // cast RNE + 2 swizzled ds_write_b128
        bf16x8 v0, v1;
        v0[0]=(bf16_t)arA[0].x; v0[1]=(bf16_t)arA[0].y; v0[2]=(bf16_t)arA[0].z; v0[3]=(bf16_t)arA[0].w;
        v0[4]=(bf16_t)arA[1].x; v0[5]=(bf16_t)arA[1].y; v0[6]=(bf16_t)arA[1].z; v0[7]=(bf16_t)arA[1].w;
        v1[0]=(bf16_t)arA[2].x; v1[1]=(bf16_t)arA[2].y; v1[2]=(bf16_t)arA[2].z; v1[3]=(bf16_t)arA[2].w;
        v1[4]=(bf16_t)arA[3].x; v1[5]=(bf16_t)arA[3].y; v1[6]=(bf16_t)arA[3].z; v1[7]=(bf16_t)arA[3].w;
        bf16_t* bufA = As[t & 1];
        *(bf16x8*)(bufA + arow * 64 + (((aq * 2    ) ^ (arow & 7)) << 3)) = v0;
        *(bf16x8*)(bufA + arow * 64 + (((aq * 2 + 1) ^ (arow & 7)) << 3)) = v1;
    };

    if (F32A) { issueA(0); asm volatile("" ::: "memory"); stageB(0); }
    else      { stage(0); }

    #pragma unroll
    for (int t = 0; t < NT; ++t) {
        if (F32A) {
            asm volatile("s_waitcnt vmcnt(2)" ::: "memory");   // A(t) loaded; B(t) may fly
            writeA(t);
            if (t + 1 < NT) {
                issueA(t + 1);
                asm volatile("" ::: "memory");                 // pin A-issue before B-issue
                stageB(t + 1);                                 // outstanding: 2+4+2 = 8
                asm volatile("s_waitcnt vmcnt(6) lgkmcnt(0)" ::: "memory"); // B(t) done, writes visible
            } else {
                asm volatile("s_waitcnt vmcnt(0) lgkmcnt(0)" ::: "memory");
            }
        } else {
            if (t + 1 < NT) {
                stage(t + 1);                                  // +4 gll -> 8 outstanding
                asm volatile("s_waitcnt vmcnt(4)" ::: "memory");
            } else {
                asm volatile("s_waitcnt vmcnt(0)" ::: "memory");
            }
        }
        __builtin_amdgcn_s_barrier();       // tile t visible to all waves
        const bf16_t* __restrict__ bufA = As[t & 1];
        const bf16_t* __restrict__ bufB = Bs[t & 1];
        bf16x8 a[2][4], b[2][2];            // [ks][frag]
        #pragma unroll
        for (int ks = 0; ks < 2; ++ks) {
            #pragma unroll
            for (int i = 0; i < 4; ++i)
                a[ks][i] = *(const bf16x8*)(bufA + (wr * 64 + i * 16 + lr) * 64
                                            + (((ks * 4 + kc) ^ (lr & 7)) << 3));
            #pragma unroll
            for (int j = 0; j < 2; ++j)
                b[ks][j] = *(const bf16x8*)(bufB + (wc * 32 + j * 16 + lr) * 64
                                            + (((ks * 4 + kc) ^ (lr & 7)) << 3));
        }
        #pragma unroll
        for (int ks = 0; ks < 2; ++ks)
            #pragma unroll
            for (int i = 0; i < 4; ++i)
                #pragma unroll
                for (int j = 0; j < 2; ++j)
                    acc[i][j] = __builtin_amdgcn_mfma_f32_16x16x32_bf16(
                        a[ks][i], b[ks][j], acc[i][j], 0, 0, 0);
        if (t + 1 < NT)
            __builtin_amdgcn_s_barrier();   // reads of buf[t&1] done before overwrite
    }

    // C/D layout: col = lane&15, row = (lane>>4)*4 + reg
    if (MODE == 0) {
        float* outF = (float*)outp;         // f32: 64B/16-lane group, coalesced
        #pragma unroll
        for (int i = 0; i < 4; ++i) {
            const int row = m0 + wr * 64 + i * 16 + kc * 4;
            #pragma unroll
            for (int j = 0; j < 2; ++j) {
                const int col = n0 + wc * 32 + j * 16 + lr;
                #pragma unroll
                for (int r = 0; r < 4; ++r)
                    outF[(size_t)(row + r) * 512 + col] = acc[i][j][r] + bv[j];
            }
        }
    } else {
        // bf16: repack via LDS (reuse As = 32 KB), then 16B/lane coalesced stores
        __syncthreads();                    // all waves done with K-loop LDS
        bf16_t* eps = &As[0][0];            // 128 x 128 bf16 = 32 KB
        #pragma unroll
        for (int i = 0; i < 4; ++i) {
            const int row = wr * 64 + i * 16 + kc * 4;
            #pragma unroll
            for (int j = 0; j < 2; ++j) {
                const int col = wc * 32 + j * 16 + lr;
                #pragma unroll
                for (int r = 0; r < 4; ++r) {
                    float v = acc[i][j][r] + bv[j];
                    if (MODE == 2) v = v / (1.f + __expf(-v));
                    eps[(row + r) * 128 + col] = (bf16_t)v;
                }
            }
        }
        __syncthreads();
        bf16_t* outB = (bf16_t*)outp;
        #pragma unroll
        for (int s2 = 0; s2 < 4; ++s2) {    // 512 thr x 8 elems = 32 rows/pass
            const int row = s2 * 32 + (tid >> 4);
            const int col = (tid & 15) * 8;
            *(bf16x8*)(outB + (size_t)(m0 + row) * 512 + n0 + col) =
                *(const bf16x8*)(eps + row * 128 + col);
        }
        if (SCAN) {
            // fused scan_partial: tile = 2 seq-chunks x 128 cols; first 256 threads.
            if (tid < 256) {
                const int chalf = tid >> 7, col = tid & 127;
                const int n = n0 + col;
                const float dec = decay_g[n];
                float st = 0.f;
                #pragma unroll 8
                for (int i = 0; i < 64; ++i)
                    st = st * dec + (float)eps[(chalf * 64 + i) * 128 + col];
                carry_g[(size_t)((m0 >> 6) + chalf) * 512 + n] = st;   // chunk = row/64
            }
        }
    }
}

// prep: weight conversion (1024 blocks) + decay (first 128 blocks). x stays f32.
__global__ void prep_all(const float* __restrict__ Wg, const float* __restrict__ Wsp,
                         const float* __restrict__ Wo, const float* __restrict__ Dp,
                         bf16_t* __restrict__ Wg_bf, bf16_t* __restrict__ Wsp_bf,
                         bf16_t* __restrict__ Wo_bf, bf16_t* __restrict__ W2_bf,
                         const float* __restrict__ A_log, float* __restrict__ decay)
{
    const int blk = blockIdx.x, tid = threadIdx.x;
    {
        int i = blk * 256 + tid;          // 512*512 elements
        Wg_bf[i]  = (bf16_t)Wg[i];
        Wsp_bf[i] = (bf16_t)Wsp[i];
        float wo  = Wo[i];
        Wo_bf[i]  = (bf16_t)wo;
        W2_bf[i]  = (bf16_t)(wo * Dp[i & 511]);   // W2[d',d] = W_out[d',d]*D[d]
    }
    if (blk < 128) {
        int d = blk * 4 + (tid >> 6);     // one wave per row of A_log
        int ll = tid & 63;
        const float* row = A_log + (size_t)d * 512;
        float s = 0.f;
        for (int k = ll; k < 512; k += 64) s += expf(row[k]);
        #pragma unroll
        for (int off = 32; off > 0; off >>= 1) s += __shfl_down(s, off);
        if (ll == 0) decay[d] = expf(-s * (1.f / 512.f));  // exp(mean(-exp(A_log)))
    }
}

// tiny cross-chunk prefix: 2048 threads, fixed trip 64 (compiler pipelines loads)
__global__ void scan_carry(const float* __restrict__ carry, const float* __restrict__ decay,
                           const float* __restrict__ state0,
                           float* __restrict__ exc, float* __restrict__ state_f)
{
    int g = blockIdx.x * 256 + threadIdx.x;       // B*N = 2048
    int n = g & 511, b = g >> 9;
    float dec = decay[n];
    float d64 = dec;
    #pragma unroll
    for (int t = 0; t < 6; ++t) d64 *= d64;       // dec^64 via squaring
    float st = state0[g];
    for (int ch = 0; ch < 64; ++ch) {
        size_t idx = (size_t)(b * 64 + ch) * 512 + n;
        exc[idx] = st;                             // exclusive carry-in per chunk
        st = st * d64 + carry[idx];
    }
    state_f[g] = st;                               // final state -> d_out tail
}

__global__ void scan_final(const bf16_t* __restrict__ s, const float* __restrict__ decay,
                           const float* __restrict__ exc, bf16_t* __restrict__ states)
{
    int g = blockIdx.x * 256 + threadIdx.x;       // B*N*64
    int n = g & 511, ch = (g >> 9) & 63, b = g >> 15;
    float dec = decay[n];
    float st = exc[(size_t)(b * 64 + ch) * 512 + n];
    size_t base = (size_t)(b * 4096 + ch * 64) * 512 + n;
    #pragma unroll 8
    for (int i = 0; i < 64; ++i) {
        st = st * dec + (float)s[base + (size_t)i * 512];
        states[base + (size_t)i * 512] = (bf16_t)st;
    }
}

extern "C" void kernel_launch(void* const* d_in, const int* in_sizes, int n_in,
                              void* d_out, int out_size, void* d_ws, size_t ws_size,
                              hipStream_t stream)
{
    const float* x      = (const float*)d_in[0];
    const float* state0 = (const float*)d_in[1];
    const float* W_gate = (const float*)d_in[2];
    const float* b_gate = (const float*)d_in[3];
    const float* W_sp   = (const float*)d_in[4];
    const float* b_sp   = (const float*)d_in[5];
    const float* W_out  = (const float*)d_in[6];
    const float* b_out  = (const float*)d_in[7];
    const float* A_log  = (const float*)d_in[8];
    const float* D_par  = (const float*)d_in[9];
    float* out = (float*)d_out;

    // workspace layout (~51.5 MB)
    char* ws = (char*)d_ws;
    bf16_t* states = (bf16_t*)ws;                     // 16 MB
    bf16_t* xg_bf  = (bf16_t*)(ws + (16u << 20));     // 16 MB
    bf16_t* s_bf   = (bf16_t*)(ws + (32u << 20));     // 16 MB
    bf16_t* Wg_bf  = (bf16_t*)(ws + (48u << 20));     // 5 x 512 KB weights
    bf16_t* Wsp_bf = Wg_bf + 262144;
    bf16_t* Wo_bf  = Wg_bf + 2 * 262144;
    bf16_t* W2_bf  = Wg_bf + 3 * 262144;
    bf16_t* WcT_bf = Wg_bf + 4 * 262144;
    float*  carry  = (float*)(Wg_bf + 5 * 262144);    // 512 KB
    float*  exc    = carry + 131072;                  // 512 KB
    float*  decay  = exc + 131072;                    // 2 KB

    prep_all<<<dim3(1024), dim3(256), 0, stream>>>(
        W_gate, W_sp, W_out, D_par, Wg_bf, Wsp_bf, Wo_bf, W2_bf, A_log, decay);

    // WcT[d',n] = sum_d W_out[d',d] * W_sp[n,d]   (M=512 -> grid 4x4 = 16)
    gemm_2ph<1, 8, false, false><<<dim3(16), dim3(512), 0, stream>>>(
        (const void*)Wo_bf, Wsp_bf, (const bf16_t*)nullptr, (const bf16_t*)nullptr,
        (const float*)nullptr, (void*)WcT_bf, (const float*)nullptr, (float*)nullptr);
    // xg = silu(x W_gate^T + b_gate)  -- A read directly as f32 (T14 reg-staged)
    gemm_2ph<2, 8, false, true><<<dim3(512), dim3(512), 0, stream>>>(
        (const void*)x, Wg_bf, (const bf16_t*)nullptr, (const bf16_t*)nullptr,
        b_gate, (void*)xg_bf, (const float*)nullptr, (float*)nullptr);
    // s = xg W_sp^T + b_sp, with fused per-chunk carry computation
    gemm_2ph<1, 8, true, false><<<dim3(512), dim3(512), 0, stream>>>(
        (const void*)xg_bf, Wsp_bf, (const bf16_t*)nullptr, (const bf16_t*)nullptr,
        b_sp, (void*)s_bf, decay, carry);

    scan_carry<<<dim3(8), dim3(256), 0, stream>>>(carry, decay, state0, exc, out + 8388608);
    scan_final<<<dim3(512), dim3(256), 0, stream>>>(s_bf, decay, exc, states);

    // out = states WcT^T + xg W2^T + b_out   (concat-K, NT=16)
    gemm_2ph<0, 16, false, false><<<dim3(512), dim3(512), 0, stream>>>(
        (const void*)states, WcT_bf, xg_bf, W2_bf, b_out, (void*)out,
        (const float*)nullptr, (float*)nullptr);
}